// Round 7
// baseline (104.103 us; speedup 1.0000x reference)
//
#include <hip/hip_runtime.h>
#include <hip/hip_cooperative_groups.h>
#include <math.h>

namespace cg = cooperative_groups;

constexpr int B_ = 8, C_ = 1280, H_ = 7, W_ = 7;
constexpr int M_ = 2048, N_ = 128, HID = 256, NC = 21;
constexpr int DET_OFF = M_ * NC;          // 43008
constexpr int IOU_OFF = M_ * NC + M_ * 4; // 51200

typedef __attribute__((ext_vector_type(8))) short bf16x8;
typedef __attribute__((ext_vector_type(8))) unsigned short u16x8;
typedef __attribute__((ext_vector_type(4))) float f32x4;

// ws layout (bytes)
constexpr size_t W1T_OFF = 0;                    // 1280*256*2 = 655360
constexpr size_t W2T_OFF = W1T_OFF + 655360;     // 256*256*2  = 131072
constexpr size_t WHT_OFF = W2T_OFF + 131072;     // 32*256*2   =  16384
constexpr size_t FMT_OFF = WHT_OFF + 16384;      // 8*49*1280*4 = 2007040

struct KParams {
    const float *fmap, *props, *bbx, *W1, *b1v, *W2, *b2v, *Wc, *bc, *Wd, *bd;
    const int *pbid, *gbid;
    float *out, *fmt;
    unsigned short *W1t, *W2t, *Wht;
};

__device__ __forceinline__ unsigned short f2bf(float f) {
    unsigned u = __builtin_bit_cast(unsigned, f);
    u += 0x7FFFu + ((u >> 16) & 1u);   // round-to-nearest-even
    return (unsigned short)(u >> 16);
}

__device__ __forceinline__ float4 max4(float4 a, float4 b) {
    return make_float4(fmaxf(a.x, b.x), fmaxf(a.y, b.y),
                       fmaxf(a.z, b.z), fmaxf(a.w, b.w));
}

// one cooperative kernel: prep+transpose | grid.sync | pool->LDS | FC1|FC2|heads|IoU
__global__ __launch_bounds__(512) void k_mega(KParams P)
{
    __shared__ __align__(16) unsigned char smem[8 * 1288 * 2];  // featL (20.6KB) / transpose tile (12.5KB)
    __shared__ unsigned short h1s[16][264];
    __shared__ unsigned short h2s[16][264];
    __shared__ float gbox[N_][4];
    __shared__ int   gids[N_];

    auto featL = (unsigned short (*)[1288])smem;
    float* tile = (float*)smem;

    const int tid  = threadIdx.x;
    const int bkid = blockIdx.x;

    if (tid < N_) {
        gbox[tid][0] = P.bbx[tid * 5 + 0];
        gbox[tid][1] = P.bbx[tid * 5 + 1];
        gbox[tid][2] = P.bbx[tid * 5 + 2];
        gbox[tid][3] = P.bbx[tid * 5 + 3];
        gids[tid] = P.gbid[tid];
    }

    // ---- phase 0: 160 transpose units + 80 W1 + 16 W2 + 1 WH = 257 units ----
    for (int u = bkid; u < 257; u += 256) {
        if (u < 160) {
            int img = u / 20, c0 = (u % 20) * 64;
            const float* src = P.fmap + ((size_t)img * C_ + c0) * 49;
            for (int i4 = tid; i4 < 784; i4 += 512)
                *(float4*)&tile[i4 * 4] = *(const float4*)(src + i4 * 4);
            __syncthreads();
            float* dst = P.fmt + (size_t)img * 49 * C_ + c0;
            for (int w4 = tid; w4 < 784; w4 += 512) {
                int px = w4 >> 4, j = w4 & 15;
                float4 v = make_float4(tile[(4 * j + 0) * 49 + px],
                                       tile[(4 * j + 1) * 49 + px],
                                       tile[(4 * j + 2) * 49 + px],
                                       tile[(4 * j + 3) * 49 + px]);
                *(float4*)(dst + (size_t)px * C_ + 4 * j) = v;
            }
        } else if (u < 240) {
            int k0 = (u - 160) * 16 + (tid >> 8) * 8;
            int col = tid & 255;
            u16x8 o;
            #pragma unroll
            for (int j = 0; j < 8; ++j) o[j] = f2bf(P.W1[(size_t)(k0 + j) * HID + col]);
            *(u16x8*)(P.W1t + (size_t)col * C_ + k0) = o;
        } else if (u < 256) {
            int k0 = (u - 240) * 16 + (tid >> 8) * 8;
            int col = tid & 255;
            u16x8 o;
            #pragma unroll
            for (int j = 0; j < 8; ++j) o[j] = f2bf(P.W2[(size_t)(k0 + j) * HID + col]);
            *(u16x8*)(P.W2t + (size_t)col * HID + k0) = o;
        } else {
            int o32 = tid & 31;
            int k0  = (tid >> 5) * 16;
            #pragma unroll
            for (int h = 0; h < 2; ++h) {
                u16x8 o;
                #pragma unroll
                for (int j = 0; j < 8; ++j) {
                    int k = k0 + h * 8 + j;
                    float v = 0.0f;
                    if (o32 < NC) v = P.Wc[(size_t)k * NC + o32];
                    else if (o32 < NC + 4) v = P.Wd[(size_t)k * 4 + (o32 - NC)];
                    o[j] = f2bf(v);
                }
                *(u16x8*)(P.Wht + (size_t)o32 * HID + k0 + h * 8) = o;
            }
        }
    }

    cg::this_grid().sync();

    const int row0 = bkid * 8;

    // ---- pool: wave = proposal (8 waves); lane = 4-ch column; 5 slabs of 256 ch ----
    {
        int p = tid >> 6, lane = tid & 63;
        int m = row0 + p;
        float4 bx = *(const float4*)(P.props + (size_t)m * 4);
        float x1 = rintf(bx.x), y1 = rintf(bx.y);
        float x2 = rintf(bx.z), y2 = rintf(bx.w);
        float rw = fmaxf(x2 - x1 + 1.0f, 1.0f);
        float rh = fmaxf(y2 - y1 + 1.0f, 1.0f);
        float bw = rw * 0.5f, bh = rh * 0.5f;
        int hs0 = __builtin_amdgcn_readfirstlane((int)fminf(fmaxf(y1, 0.f), 7.f));
        int he0 = __builtin_amdgcn_readfirstlane((int)fminf(fmaxf(ceilf(bh) + y1, 0.f), 7.f));
        int hs1 = __builtin_amdgcn_readfirstlane((int)fminf(fmaxf(floorf(bh) + y1, 0.f), 7.f));
        int he1 = __builtin_amdgcn_readfirstlane((int)fminf(fmaxf(ceilf(2.f * bh) + y1, 0.f), 7.f));
        int ws0 = __builtin_amdgcn_readfirstlane((int)fminf(fmaxf(x1, 0.f), 7.f));
        int we0 = __builtin_amdgcn_readfirstlane((int)fminf(fmaxf(ceilf(bw) + x1, 0.f), 7.f));
        int ws1 = __builtin_amdgcn_readfirstlane((int)fminf(fmaxf(floorf(bw) + x1, 0.f), 7.f));
        int we1 = __builtin_amdgcn_readfirstlane((int)fminf(fmaxf(ceilf(2.f * bw) + x1, 0.f), 7.f));
        int bid = __builtin_amdgcn_readfirstlane(P.pbid[m]);

        bool e00 = (he0 <= hs0) | (we0 <= ws0);
        bool e01 = (he0 <= hs0) | (we1 <= ws1);
        bool e10 = (he1 <= hs1) | (we0 <= ws0);
        bool e11 = (he1 <= hs1) | (we1 <= ws1);

        const float* base = P.fmt + ((size_t)bid * 49) * C_ + lane * 4;
        const float4 ninf = make_float4(-INFINITY, -INFINITY, -INFINITY, -INFINITY);
        const float4 z    = make_float4(0.f, 0.f, 0.f, 0.f);

        for (int s = 0; s < 5; ++s) {
            const float* bs = base + s * 256;
            float4 b00 = ninf, b01 = ninf, b10 = ninf, b11 = ninf;
            for (int y = hs0; y < he1; ++y) {
                const float* rp = bs + (y * 7) * C_;
                float4 v[7];
                #pragma unroll
                for (int x = 0; x < 7; ++x) v[x] = *(const float4*)(rp + x * C_);
                float4 r0 = ninf, r1 = ninf;
                #pragma unroll
                for (int x = 0; x < 7; ++x) {
                    if (x >= ws0 && x < we0) r0 = max4(r0, v[x]);
                    if (x >= ws1 && x < we1) r1 = max4(r1, v[x]);
                }
                if (y < he0)  { b00 = max4(b00, r0); b01 = max4(b01, r1); }
                if (y >= hs1) { b10 = max4(b10, r0); b11 = max4(b11, r1); }
            }
            float4 f00 = e00 ? z : b00;
            float4 f01 = e01 ? z : b01;
            float4 f10 = e10 ? z : b10;
            float4 f11 = e11 ? z : b11;
            ushort4 o;
            o.x = f2bf((f00.x + f01.x + f10.x + f11.x) * 0.25f);
            o.y = f2bf((f00.y + f01.y + f10.y + f11.y) * 0.25f);
            o.z = f2bf((f00.z + f01.z + f10.z + f11.z) * 0.25f);
            o.w = f2bf((f00.w + f01.w + f10.w + f11.w) * 0.25f);
            *(ushort4*)&featL[p][s * 256 + lane * 4] = o;
        }
    }
    __syncthreads();

    const int w = tid >> 6, lane = tid & 63;
    const int r = lane & 15, g = lane >> 4;
    const int col0 = w * 32;                  // wave covers 32 cols

    // ---- FC1: A from LDS, B prefetched from L2 ----
    f32x4 acc0 = (f32x4){0.f, 0.f, 0.f, 0.f};
    f32x4 acc1 = (f32x4){0.f, 0.f, 0.f, 0.f};
    const unsigned short* arp = featL[r & 7];
    const unsigned short* bp0 = P.W1t + (size_t)(col0 + r) * C_ + g * 8;
    const unsigned short* bp1 = bp0 + 16 * C_;

    bf16x8 a_c  = *(const bf16x8*)(arp + g * 8);
    bf16x8 b0_c = *(const bf16x8*)bp0;
    bf16x8 b1_c = *(const bf16x8*)bp1;
    for (int ks = 1; ks < 40; ++ks) {
        bf16x8 a_n  = *(const bf16x8*)(arp + ks * 32 + g * 8);
        bf16x8 b0_n = *(const bf16x8*)(bp0 + ks * 32);
        bf16x8 b1_n = *(const bf16x8*)(bp1 + ks * 32);
        acc0 = __builtin_amdgcn_mfma_f32_16x16x32_bf16(a_c, b0_c, acc0, 0, 0, 0);
        acc1 = __builtin_amdgcn_mfma_f32_16x16x32_bf16(a_c, b1_c, acc1, 0, 0, 0);
        a_c = a_n; b0_c = b0_n; b1_c = b1_n;
    }
    acc0 = __builtin_amdgcn_mfma_f32_16x16x32_bf16(a_c, b0_c, acc0, 0, 0, 0);
    acc1 = __builtin_amdgcn_mfma_f32_16x16x32_bf16(a_c, b1_c, acc1, 0, 0, 0);

    {
        int colA = col0 + r, colB = col0 + 16 + r;
        float biasA = P.b1v[colA], biasB = P.b1v[colB];
        #pragma unroll
        for (int i = 0; i < 4; ++i) {
            h1s[g * 4 + i][colA] = f2bf(fmaxf(acc0[i] + biasA, 0.f));
            h1s[g * 4 + i][colB] = f2bf(fmaxf(acc1[i] + biasB, 0.f));
        }
    }
    __syncthreads();

    // ---- FC2 ----
    f32x4 c0v = (f32x4){0.f, 0.f, 0.f, 0.f};
    f32x4 c1v = (f32x4){0.f, 0.f, 0.f, 0.f};
    const unsigned short* bq0 = P.W2t + (size_t)(col0 + r) * HID + g * 8;
    const unsigned short* bq1 = bq0 + 16 * HID;
    #pragma unroll
    for (int ks = 0; ks < 8; ++ks) {
        bf16x8 a  = *(const bf16x8*)(&h1s[r][ks * 32 + g * 8]);
        bf16x8 u0 = *(const bf16x8*)(bq0 + ks * 32);
        bf16x8 u1 = *(const bf16x8*)(bq1 + ks * 32);
        c0v = __builtin_amdgcn_mfma_f32_16x16x32_bf16(a, u0, c0v, 0, 0, 0);
        c1v = __builtin_amdgcn_mfma_f32_16x16x32_bf16(a, u1, c1v, 0, 0, 0);
    }
    {
        int colA = col0 + r, colB = col0 + 16 + r;
        float biasA = P.b2v[colA], biasB = P.b2v[colB];
        #pragma unroll
        for (int i = 0; i < 4; ++i) {
            h2s[g * 4 + i][colA] = f2bf(c0v[i] + biasA);
            h2s[g * 4 + i][colB] = f2bf(c1v[i] + biasB);
        }
    }
    __syncthreads();

    // ---- heads on wave 0 (rows 0..7 valid) ----
    if (w == 0) {
        f32x4 acc3[2];
        #pragma unroll
        for (int f = 0; f < 2; ++f) acc3[f] = (f32x4){0.f, 0.f, 0.f, 0.f};
        const unsigned short* bp3 = P.Wht + (size_t)r * HID + g * 8;
        #pragma unroll
        for (int ks = 0; ks < 8; ++ks) {
            bf16x8 a = *(const bf16x8*)(&h2s[r][ks * 32 + g * 8]);
            #pragma unroll
            for (int f = 0; f < 2; ++f) {
                bf16x8 b = *(const bf16x8*)(bp3 + (size_t)f * 16 * HID + ks * 32);
                acc3[f] = __builtin_amdgcn_mfma_f32_16x16x32_bf16(a, b, acc3[f], 0, 0, 0);
            }
        }
        if (g < 2) {
            #pragma unroll
            for (int f = 0; f < 2; ++f) {
                int col = f * 16 + r;
                #pragma unroll
                for (int i = 0; i < 4; ++i) {
                    int m = row0 + g * 4 + i;
                    if (col < NC)
                        P.out[(size_t)m * NC + col] = acc3[f][i] + P.bc[col];
                    else if (col < NC + 4)
                        P.out[DET_OFF + (size_t)m * 4 + (col - NC)] = acc3[f][i] + P.bd[col - NC];
                }
            }
        }
    }

    // ---- IoU: wave w handles proposal row0+w ----
    {
        int m = row0 + w;
        float4 bxp = *(const float4*)(P.props + (size_t)m * 4);
        float ap2 = (bxp.z - bxp.x) * (bxp.w - bxp.y);
        int pb = P.pbid[m];
        float best = 0.0f;
        for (int n = lane; n < N_; n += 64) {
            if (gids[n] == pb) {
                float ix = fmaxf(fminf(bxp.z, gbox[n][2]) - fmaxf(bxp.x, gbox[n][0]), 0.0f);
                float iy = fmaxf(fminf(bxp.w, gbox[n][3]) - fmaxf(bxp.y, gbox[n][1]), 0.0f);
                float inter = ix * iy;
                float ag = (gbox[n][2] - gbox[n][0]) * (gbox[n][3] - gbox[n][1]);
                float un = fmaxf(ap2 + ag - inter, 1e-6f);
                best = fmaxf(best, inter / un);
            }
        }
        #pragma unroll
        for (int off = 32; off; off >>= 1)
            best = fmaxf(best, __shfl_xor(best, off));
        if (lane == 0) P.out[IOU_OFF + m] = best;
    }
}

extern "C" void kernel_launch(void* const* d_in, const int* in_sizes, int n_in,
                              void* d_out, int out_size, void* d_ws, size_t ws_size,
                              hipStream_t stream) {
    char* ws = (char*)d_ws;
    KParams prm;
    prm.fmap  = (const float*)d_in[0];
    prm.props = (const float*)d_in[1];
    prm.bbx   = (const float*)d_in[2];
    prm.W1    = (const float*)d_in[3];
    prm.b1v   = (const float*)d_in[4];
    prm.W2    = (const float*)d_in[5];
    prm.b2v   = (const float*)d_in[6];
    prm.Wc    = (const float*)d_in[7];
    prm.bc    = (const float*)d_in[8];
    prm.Wd    = (const float*)d_in[9];
    prm.bd    = (const float*)d_in[10];
    prm.pbid  = (const int*)d_in[11];
    prm.gbid  = (const int*)d_in[12];
    prm.out   = (float*)d_out;
    prm.fmt   = (float*)(ws + FMT_OFF);
    prm.W1t   = (unsigned short*)(ws + W1T_OFF);
    prm.W2t   = (unsigned short*)(ws + W2T_OFF);
    prm.Wht   = (unsigned short*)(ws + WHT_OFF);

    void* args[] = {&prm};
    hipLaunchCooperativeKernel((void*)k_mega, dim3(256), dim3(512), args, 0, stream);
}

// Round 8
// 44.493 us; speedup vs baseline: 2.3398x; 2.3398x over previous
//
#include <hip/hip_runtime.h>
#include <math.h>

constexpr int B_ = 8, C_ = 1280, H_ = 7, W_ = 7;
constexpr int M_ = 2048, N_ = 128, HID = 256, NC = 21;
constexpr int DET_OFF = M_ * NC;          // 43008
constexpr int IOU_OFF = M_ * NC + M_ * 4; // 51200
constexpr int NRECT = 784;                // 28 y-intervals x 28 x-intervals

typedef __attribute__((ext_vector_type(8))) short bf16x8;
typedef __attribute__((ext_vector_type(8))) unsigned short u16x8;
typedef __attribute__((ext_vector_type(4))) float f32x4;

// ws layout (bytes)
constexpr size_t W1T_OFF = 0;                    // 1280*256*2 = 655360
constexpr size_t W2T_OFF = W1T_OFF + 655360;     // 256*256*2  = 131072
constexpr size_t WHT_OFF = W2T_OFF + 131072;     // 32*256*2   =  16384
constexpr size_t AM_OFF  = WHT_OFF + 16384;      // 8*784*1280*2 = 16056320

// k_aux grid partitions
constexpr int RECT_BLKS    = B_ * 40;   // (img, 32-ch group) = 320
constexpr int PREP_W1_BLKS = 160;       // 1280*256 / (256*8)
constexpr int PREP_W2_BLKS = 32;
constexpr int PREP_WH_BLKS = 4;
constexpr int AUX_BLKS = RECT_BLKS + PREP_W1_BLKS + PREP_W2_BLKS + PREP_WH_BLKS; // 516

__device__ __forceinline__ unsigned short f2bf(float f) {
    unsigned u = __builtin_bit_cast(unsigned, f);
    u += 0x7FFFu + ((u >> 16) & 1u);   // round-to-nearest-even
    return (unsigned short)(u >> 16);
}
__device__ __forceinline__ float bf2f(unsigned short u) {
    return __builtin_bit_cast(float, (unsigned)u << 16);
}
// interval index for 0 <= s < e <= 7  ->  [0,28)
__device__ __forceinline__ int ivix(int s, int e) {
    return s * 7 - ((s * (s - 1)) >> 1) + (e - s - 1);
}

// ---------- k_aux: rect-max precompute + weight prep ----------
__global__ __launch_bounds__(256) void k_aux(
    const float* __restrict__ fmap,
    const float* __restrict__ W1, const float* __restrict__ W2,
    const float* __restrict__ Wc, const float* __restrict__ Wd,
    unsigned short* __restrict__ allmax, unsigned short* __restrict__ W1t,
    unsigned short* __restrict__ W2t,    unsigned short* __restrict__ Wht)
{
    __shared__ __align__(16) float tile[32 * 49];                 // 6.1 KB
    __shared__ __align__(16) unsigned short rect_lds[NRECT][36];  // 56.4 KB (pad 36)

    const int tid = threadIdx.x;
    const int b = blockIdx.x;

    if (b < RECT_BLKS) {
        int img = b / 40, c0 = (b % 40) * 32;
        const float* src = fmap + ((size_t)img * C_ + c0) * 49;
        for (int i4 = tid; i4 < 392; i4 += 256)
            *(float4*)&tile[i4 * 4] = *(const float4*)(src + i4 * 4);
        __syncthreads();

        int c = tid >> 3, sy = tid & 7;   // c in [0,32), sy in [0,8)
        if (sy < 7) {
            const float* tc = tile + c * 49;
            float colacc[7];
            #pragma unroll
            for (int x = 0; x < 7; ++x) colacc[x] = -INFINITY;
            for (int ey = sy + 1; ey <= 7; ++ey) {
                int y = ey - 1;
                #pragma unroll
                for (int x = 0; x < 7; ++x)
                    colacc[x] = fmaxf(colacc[x], tc[y * 7 + x]);
                int yi = ivix(sy, ey);
                int xi = 0;
                #pragma unroll
                for (int sx = 0; sx < 7; ++sx) {
                    float mx = -INFINITY;
                    #pragma unroll
                    for (int ex = sx + 1; ex <= 7; ++ex) {
                        mx = fmaxf(mx, colacc[ex - 1]);
                        rect_lds[yi * 28 + xi][c] = f2bf(mx);
                        ++xi;
                    }
                }
            }
        }
        __syncthreads();

        // writeback: 784 rects x 32 ch -> [img][rect][C] (64B per rect row chunk)
        unsigned short* dst = allmax + (size_t)img * NRECT * C_ + c0;
        for (int i = tid; i < NRECT * 4; i += 256) {
            int rid = i >> 2, ch = (i & 3) * 8;
            ushort4 lo = *(const ushort4*)&rect_lds[rid][ch];
            ushort4 hi = *(const ushort4*)&rect_lds[rid][ch + 4];
            unsigned short* dp = dst + (size_t)rid * C_ + ch;
            *(ushort4*)dp = lo;
            *(ushort4*)(dp + 4) = hi;
        }
    } else if (b < RECT_BLKS + PREP_W1_BLKS) {
        int k0 = (b - RECT_BLKS) * 8;
        int col = tid;
        u16x8 o;
        #pragma unroll
        for (int j = 0; j < 8; ++j) o[j] = f2bf(W1[(size_t)(k0 + j) * HID + col]);
        *(u16x8*)(W1t + (size_t)col * C_ + k0) = o;
    } else if (b < RECT_BLKS + PREP_W1_BLKS + PREP_W2_BLKS) {
        int k0 = (b - RECT_BLKS - PREP_W1_BLKS) * 8;
        int col = tid;
        u16x8 o;
        #pragma unroll
        for (int j = 0; j < 8; ++j) o[j] = f2bf(W2[(size_t)(k0 + j) * HID + col]);
        *(u16x8*)(W2t + (size_t)col * HID + k0) = o;
    } else {
        int i = (b - RECT_BLKS - PREP_W1_BLKS - PREP_W2_BLKS) * 256 + tid;
        int o32 = i & 31;
        int k0  = (i >> 5) * 8;
        u16x8 o;
        #pragma unroll
        for (int j = 0; j < 8; ++j) {
            float v = 0.0f;
            if (o32 < NC) v = Wc[(size_t)(k0 + j) * NC + o32];
            else if (o32 < NC + 4) v = Wd[(size_t)(k0 + j) * 4 + (o32 - NC)];
            o[j] = f2bf(v);
        }
        *(u16x8*)(Wht + (size_t)o32 * HID + k0) = o;
    }
}

// ---------- k_fc: gather-pool -> FC1 -> FC2 -> heads + IoU; 8 proposals/block ----------
__global__ __launch_bounds__(512) void k_fc(
    const unsigned short* __restrict__ allmax,
    const unsigned short* __restrict__ W1t,
    const unsigned short* __restrict__ W2t,
    const unsigned short* __restrict__ Wht,
    const float* __restrict__ b1v, const float* __restrict__ b2v,
    const float* __restrict__ bc,  const float* __restrict__ bd,
    const float* __restrict__ props, const int* __restrict__ pbid,
    const float* __restrict__ bbx,   const int* __restrict__ gbid,
    float* __restrict__ out)
{
    __shared__ unsigned short featL[8][1288];   // 20.6 KB
    __shared__ unsigned short h1s[16][264];
    __shared__ unsigned short h2s[16][264];
    __shared__ float gbox[N_][4];
    __shared__ int   gids[N_];

    const int tid = threadIdx.x;
    const int row0 = blockIdx.x * 8;

    if (tid < N_) {
        gbox[tid][0] = bbx[tid * 5 + 0];
        gbox[tid][1] = bbx[tid * 5 + 1];
        gbox[tid][2] = bbx[tid * 5 + 2];
        gbox[tid][3] = bbx[tid * 5 + 3];
        gids[tid] = gbid[tid];
    }

    // ---- gather-pool: wave = proposal; 4 rect-row gathers per 256-ch chunk ----
    {
        int p = tid >> 6, lane = tid & 63;
        int m = row0 + p;
        float4 bx = *(const float4*)(props + (size_t)m * 4);
        float x1 = rintf(bx.x), y1 = rintf(bx.y);
        float x2 = rintf(bx.z), y2 = rintf(bx.w);
        float rw = fmaxf(x2 - x1 + 1.0f, 1.0f);
        float rh = fmaxf(y2 - y1 + 1.0f, 1.0f);
        float bw = rw * 0.5f, bh = rh * 0.5f;
        int hs0 = __builtin_amdgcn_readfirstlane((int)fminf(fmaxf(y1, 0.f), 7.f));
        int he0 = __builtin_amdgcn_readfirstlane((int)fminf(fmaxf(ceilf(bh) + y1, 0.f), 7.f));
        int hs1 = __builtin_amdgcn_readfirstlane((int)fminf(fmaxf(floorf(bh) + y1, 0.f), 7.f));
        int he1 = __builtin_amdgcn_readfirstlane((int)fminf(fmaxf(ceilf(2.f * bh) + y1, 0.f), 7.f));
        int ws0 = __builtin_amdgcn_readfirstlane((int)fminf(fmaxf(x1, 0.f), 7.f));
        int we0 = __builtin_amdgcn_readfirstlane((int)fminf(fmaxf(ceilf(bw) + x1, 0.f), 7.f));
        int ws1 = __builtin_amdgcn_readfirstlane((int)fminf(fmaxf(floorf(bw) + x1, 0.f), 7.f));
        int we1 = __builtin_amdgcn_readfirstlane((int)fminf(fmaxf(ceilf(2.f * bw) + x1, 0.f), 7.f));
        int bid = __builtin_amdgcn_readfirstlane(pbid[m]);

        int v00 = (he0 > hs0) & (we0 > ws0);
        int v01 = (he0 > hs0) & (we1 > ws1);
        int v10 = (he1 > hs1) & (we0 > ws0);
        int v11 = (he1 > hs1) & (we1 > ws1);
        int yi0 = v00 | v01 ? ivix(hs0, max(he0, hs0 + 1)) : 0;
        int yi1 = v10 | v11 ? ivix(hs1, max(he1, hs1 + 1)) : 0;
        int xi0 = v00 | v10 ? ivix(ws0, max(we0, ws0 + 1)) : 0;
        int xi1 = v01 | v11 ? ivix(ws1, max(we1, ws1 + 1)) : 0;
        const unsigned short* base = allmax + (size_t)bid * NRECT * C_;
        const unsigned short* a00 = base + (size_t)(yi0 * 28 + xi0) * C_;
        const unsigned short* a01 = base + (size_t)(yi0 * 28 + xi1) * C_;
        const unsigned short* a10 = base + (size_t)(yi1 * 28 + xi0) * C_;
        const unsigned short* a11 = base + (size_t)(yi1 * 28 + xi1) * C_;
        float m00 = v00 ? 0.25f : 0.0f;
        float m01 = v01 ? 0.25f : 0.0f;
        float m10 = v10 ? 0.25f : 0.0f;
        float m11 = v11 ? 0.25f : 0.0f;

        for (int it = 0; it < 5; ++it) {
            int c = it * 256 + lane * 4;
            ushort4 u0 = *(const ushort4*)(a00 + c);
            ushort4 u1 = *(const ushort4*)(a01 + c);
            ushort4 u2 = *(const ushort4*)(a10 + c);
            ushort4 u3 = *(const ushort4*)(a11 + c);
            ushort4 o;
            o.x = f2bf(bf2f(u0.x) * m00 + bf2f(u1.x) * m01 + bf2f(u2.x) * m10 + bf2f(u3.x) * m11);
            o.y = f2bf(bf2f(u0.y) * m00 + bf2f(u1.y) * m01 + bf2f(u2.y) * m10 + bf2f(u3.y) * m11);
            o.z = f2bf(bf2f(u0.z) * m00 + bf2f(u1.z) * m01 + bf2f(u2.z) * m10 + bf2f(u3.z) * m11);
            o.w = f2bf(bf2f(u0.w) * m00 + bf2f(u1.w) * m01 + bf2f(u2.w) * m10 + bf2f(u3.w) * m11);
            *(ushort4*)&featL[p][c] = o;
        }
    }
    __syncthreads();

    const int w = tid >> 6, lane = tid & 63;
    const int r = lane & 15, g = lane >> 4;
    const int col0 = w * 32;

    // ---- FC1: A from LDS, B depth-2 prefetch from L2 ----
    f32x4 acc0 = (f32x4){0.f, 0.f, 0.f, 0.f};
    f32x4 acc1 = (f32x4){0.f, 0.f, 0.f, 0.f};
    const unsigned short* arp = featL[r & 7] + g * 8;
    const unsigned short* bp0 = W1t + (size_t)(col0 + r) * C_ + g * 8;
    const unsigned short* bp1 = bp0 + 16 * C_;

    bf16x8 aA = *(const bf16x8*)arp;
    bf16x8 bA0 = *(const bf16x8*)bp0;
    bf16x8 bA1 = *(const bf16x8*)bp1;
    bf16x8 aB = *(const bf16x8*)(arp + 32);
    bf16x8 bB0 = *(const bf16x8*)(bp0 + 32);
    bf16x8 bB1 = *(const bf16x8*)(bp1 + 32);
    for (int ks = 2; ks < 40; ++ks) {
        bf16x8 aN  = *(const bf16x8*)(arp + ks * 32);
        bf16x8 bN0 = *(const bf16x8*)(bp0 + ks * 32);
        bf16x8 bN1 = *(const bf16x8*)(bp1 + ks * 32);
        acc0 = __builtin_amdgcn_mfma_f32_16x16x32_bf16(aA, bA0, acc0, 0, 0, 0);
        acc1 = __builtin_amdgcn_mfma_f32_16x16x32_bf16(aA, bA1, acc1, 0, 0, 0);
        aA = aB; bA0 = bB0; bA1 = bB1;
        aB = aN; bB0 = bN0; bB1 = bN1;
    }
    acc0 = __builtin_amdgcn_mfma_f32_16x16x32_bf16(aA, bA0, acc0, 0, 0, 0);
    acc1 = __builtin_amdgcn_mfma_f32_16x16x32_bf16(aA, bA1, acc1, 0, 0, 0);
    acc0 = __builtin_amdgcn_mfma_f32_16x16x32_bf16(aB, bB0, acc0, 0, 0, 0);
    acc1 = __builtin_amdgcn_mfma_f32_16x16x32_bf16(aB, bB1, acc1, 0, 0, 0);

    {
        int colA = col0 + r, colB = col0 + 16 + r;
        float biasA = b1v[colA], biasB = b1v[colB];
        #pragma unroll
        for (int i = 0; i < 4; ++i) {
            h1s[g * 4 + i][colA] = f2bf(fmaxf(acc0[i] + biasA, 0.f));
            h1s[g * 4 + i][colB] = f2bf(fmaxf(acc1[i] + biasB, 0.f));
        }
    }
    __syncthreads();

    // ---- FC2 ----
    f32x4 c0v = (f32x4){0.f, 0.f, 0.f, 0.f};
    f32x4 c1v = (f32x4){0.f, 0.f, 0.f, 0.f};
    const unsigned short* bq0 = W2t + (size_t)(col0 + r) * HID + g * 8;
    const unsigned short* bq1 = bq0 + 16 * HID;
    #pragma unroll
    for (int ks = 0; ks < 8; ++ks) {
        bf16x8 a  = *(const bf16x8*)(&h1s[r][ks * 32 + g * 8]);
        bf16x8 u0 = *(const bf16x8*)(bq0 + ks * 32);
        bf16x8 u1 = *(const bf16x8*)(bq1 + ks * 32);
        c0v = __builtin_amdgcn_mfma_f32_16x16x32_bf16(a, u0, c0v, 0, 0, 0);
        c1v = __builtin_amdgcn_mfma_f32_16x16x32_bf16(a, u1, c1v, 0, 0, 0);
    }
    {
        int colA = col0 + r, colB = col0 + 16 + r;
        float biasA = b2v[colA], biasB = b2v[colB];
        #pragma unroll
        for (int i = 0; i < 4; ++i) {
            h2s[g * 4 + i][colA] = f2bf(c0v[i] + biasA);
            h2s[g * 4 + i][colB] = f2bf(c1v[i] + biasB);
        }
    }
    __syncthreads();

    // ---- heads on wave 0 (rows 0..7 valid) ----
    if (w == 0) {
        f32x4 acc3[2];
        #pragma unroll
        for (int f = 0; f < 2; ++f) acc3[f] = (f32x4){0.f, 0.f, 0.f, 0.f};
        const unsigned short* bp3 = Wht + (size_t)r * HID + g * 8;
        #pragma unroll
        for (int ks = 0; ks < 8; ++ks) {
            bf16x8 a = *(const bf16x8*)(&h2s[r][ks * 32 + g * 8]);
            #pragma unroll
            for (int f = 0; f < 2; ++f) {
                bf16x8 b = *(const bf16x8*)(bp3 + (size_t)f * 16 * HID + ks * 32);
                acc3[f] = __builtin_amdgcn_mfma_f32_16x16x32_bf16(a, b, acc3[f], 0, 0, 0);
            }
        }
        if (g < 2) {
            #pragma unroll
            for (int f = 0; f < 2; ++f) {
                int col = f * 16 + r;
                #pragma unroll
                for (int i = 0; i < 4; ++i) {
                    int m = row0 + g * 4 + i;
                    if (col < NC)
                        out[(size_t)m * NC + col] = acc3[f][i] + bc[col];
                    else if (col < NC + 4)
                        out[DET_OFF + (size_t)m * 4 + (col - NC)] = acc3[f][i] + bd[col - NC];
                }
            }
        }
    }

    // ---- IoU: wave w handles proposal row0+w ----
    {
        int m = row0 + w;
        float4 bxp = *(const float4*)(props + (size_t)m * 4);
        float ap2 = (bxp.z - bxp.x) * (bxp.w - bxp.y);
        int pb = pbid[m];
        float best = 0.0f;
        for (int n = lane; n < N_; n += 64) {
            if (gids[n] == pb) {
                float ix = fmaxf(fminf(bxp.z, gbox[n][2]) - fmaxf(bxp.x, gbox[n][0]), 0.0f);
                float iy = fmaxf(fminf(bxp.w, gbox[n][3]) - fmaxf(bxp.y, gbox[n][1]), 0.0f);
                float inter = ix * iy;
                float ag = (gbox[n][2] - gbox[n][0]) * (gbox[n][3] - gbox[n][1]);
                float un = fmaxf(ap2 + ag - inter, 1e-6f);
                best = fmaxf(best, inter / un);
            }
        }
        #pragma unroll
        for (int off = 32; off; off >>= 1)
            best = fmaxf(best, __shfl_xor(best, off));
        if (lane == 0) out[IOU_OFF + m] = best;
    }
}

extern "C" void kernel_launch(void* const* d_in, const int* in_sizes, int n_in,
                              void* d_out, int out_size, void* d_ws, size_t ws_size,
                              hipStream_t stream) {
    const float* fmap  = (const float*)d_in[0];
    const float* props = (const float*)d_in[1];
    const float* bbx   = (const float*)d_in[2];
    const float* W1    = (const float*)d_in[3];
    const float* b1v   = (const float*)d_in[4];
    const float* W2    = (const float*)d_in[5];
    const float* b2v   = (const float*)d_in[6];
    const float* Wc    = (const float*)d_in[7];
    const float* bc    = (const float*)d_in[8];
    const float* Wd    = (const float*)d_in[9];
    const float* bd    = (const float*)d_in[10];
    const int*   pbid  = (const int*)d_in[11];
    const int*   gbid  = (const int*)d_in[12];
    float* out = (float*)d_out;

    char* ws = (char*)d_ws;
    unsigned short* W1t    = (unsigned short*)(ws + W1T_OFF);
    unsigned short* W2t    = (unsigned short*)(ws + W2T_OFF);
    unsigned short* Wht    = (unsigned short*)(ws + WHT_OFF);
    unsigned short* allmax = (unsigned short*)(ws + AM_OFF);

    k_aux<<<dim3(AUX_BLKS), dim3(256), 0, stream>>>(
        fmap, W1, W2, Wc, Wd, allmax, W1t, W2t, Wht);
    k_fc<<<dim3(M_ / 8), dim3(512), 0, stream>>>(
        allmax, W1t, W2t, Wht, b1v, b2v, bc, bd, props, pbid, bbx, gbid, out);
}

// Round 9
// 44.247 us; speedup vs baseline: 2.3528x; 1.0056x over previous
//
#include <hip/hip_runtime.h>
#include <math.h>

constexpr int B_ = 8, C_ = 1280, H_ = 7, W_ = 7;
constexpr int M_ = 2048, N_ = 128, HID = 256, NC = 21;
constexpr int DET_OFF = M_ * NC;          // 43008
constexpr int IOU_OFF = M_ * NC + M_ * 4; // 51200
constexpr int NRECT = 784;                // 28 y-intervals x 28 x-intervals

typedef __attribute__((ext_vector_type(8))) short bf16x8;
typedef __attribute__((ext_vector_type(8))) unsigned short u16x8;
typedef __attribute__((ext_vector_type(4))) float f32x4;

// ws layout (bytes)
constexpr size_t W1T_OFF = 0;                    // 1280*256*2 = 655360
constexpr size_t W2T_OFF = W1T_OFF + 655360;     // 256*256*2  = 131072
constexpr size_t WHT_OFF = W2T_OFF + 131072;     // 32*256*2   =  16384
constexpr size_t AM_OFF  = WHT_OFF + 16384;      // 8*784*1280*2 = 16056320

// k_aux grid partitions
constexpr int RECT_BLKS    = B_ * 40;   // (img, 32-ch group) = 320
constexpr int PREP_W1_BLKS = 160;       // 1280*256 / (256*8)
constexpr int PREP_W2_BLKS = 32;
constexpr int PREP_WH_BLKS = 4;
constexpr int AUX_BLKS = RECT_BLKS + PREP_W1_BLKS + PREP_W2_BLKS + PREP_WH_BLKS; // 516

__device__ __forceinline__ unsigned short f2bf(float f) {
    unsigned u = __builtin_bit_cast(unsigned, f);
    u += 0x7FFFu + ((u >> 16) & 1u);   // round-to-nearest-even
    return (unsigned short)(u >> 16);
}
__device__ __forceinline__ float bf2f(unsigned short u) {
    return __builtin_bit_cast(float, (unsigned)u << 16);
}
// interval index for 0 <= s < e <= 7  ->  [0,28)
__device__ __forceinline__ int ivix(int s, int e) {
    return s * 7 - ((s * (s - 1)) >> 1) + (e - s - 1);
}

// ---------- k_aux: rect-max precompute + weight prep ----------
__global__ __launch_bounds__(256) void k_aux(
    const float* __restrict__ fmap,
    const float* __restrict__ W1, const float* __restrict__ W2,
    const float* __restrict__ Wc, const float* __restrict__ Wd,
    unsigned short* __restrict__ allmax, unsigned short* __restrict__ W1t,
    unsigned short* __restrict__ W2t,    unsigned short* __restrict__ Wht)
{
    __shared__ __align__(16) float tile[32 * 49];                 // 6.1 KB
    __shared__ __align__(16) unsigned short rect_lds[NRECT][36];  // 56.4 KB (pad 36)

    const int tid = threadIdx.x;
    const int b = blockIdx.x;

    if (b < RECT_BLKS) {
        int img = b / 40, c0 = (b % 40) * 32;
        const float* src = fmap + ((size_t)img * C_ + c0) * 49;
        for (int i4 = tid; i4 < 392; i4 += 256)
            *(float4*)&tile[i4 * 4] = *(const float4*)(src + i4 * 4);
        __syncthreads();

        int c = tid >> 3, sy = tid & 7;   // c in [0,32), sy in [0,8)
        if (sy < 7) {
            const float* tc = tile + c * 49;
            float colacc[7];
            #pragma unroll
            for (int x = 0; x < 7; ++x) colacc[x] = -INFINITY;
            for (int ey = sy + 1; ey <= 7; ++ey) {
                int y = ey - 1;
                #pragma unroll
                for (int x = 0; x < 7; ++x)
                    colacc[x] = fmaxf(colacc[x], tc[y * 7 + x]);
                int yi = ivix(sy, ey);
                int xi = 0;
                #pragma unroll
                for (int sx = 0; sx < 7; ++sx) {
                    float mx = -INFINITY;
                    #pragma unroll
                    for (int ex = sx + 1; ex <= 7; ++ex) {
                        mx = fmaxf(mx, colacc[ex - 1]);
                        rect_lds[yi * 28 + xi][c] = f2bf(mx);
                        ++xi;
                    }
                }
            }
        }
        __syncthreads();

        // writeback: 784 rects x 32 ch -> [img][rect][C]
        unsigned short* dst = allmax + (size_t)img * NRECT * C_ + c0;
        for (int i = tid; i < NRECT * 4; i += 256) {
            int rid = i >> 2, ch = (i & 3) * 8;
            ushort4 lo = *(const ushort4*)&rect_lds[rid][ch];
            ushort4 hi = *(const ushort4*)&rect_lds[rid][ch + 4];
            unsigned short* dp = dst + (size_t)rid * C_ + ch;
            *(ushort4*)dp = lo;
            *(ushort4*)(dp + 4) = hi;
        }
    } else if (b < RECT_BLKS + PREP_W1_BLKS) {
        int k0 = (b - RECT_BLKS) * 8;
        int col = tid;
        u16x8 o;
        #pragma unroll
        for (int j = 0; j < 8; ++j) o[j] = f2bf(W1[(size_t)(k0 + j) * HID + col]);
        *(u16x8*)(W1t + (size_t)col * C_ + k0) = o;
    } else if (b < RECT_BLKS + PREP_W1_BLKS + PREP_W2_BLKS) {
        int k0 = (b - RECT_BLKS - PREP_W1_BLKS) * 8;
        int col = tid;
        u16x8 o;
        #pragma unroll
        for (int j = 0; j < 8; ++j) o[j] = f2bf(W2[(size_t)(k0 + j) * HID + col]);
        *(u16x8*)(W2t + (size_t)col * HID + k0) = o;
    } else {
        int i = (b - RECT_BLKS - PREP_W1_BLKS - PREP_W2_BLKS) * 256 + tid;
        int o32 = i & 31;
        int k0  = (i >> 5) * 8;
        u16x8 o;
        #pragma unroll
        for (int j = 0; j < 8; ++j) {
            float v = 0.0f;
            if (o32 < NC) v = Wc[(size_t)(k0 + j) * NC + o32];
            else if (o32 < NC + 4) v = Wd[(size_t)(k0 + j) * 4 + (o32 - NC)];
            o[j] = f2bf(v);
        }
        *(u16x8*)(Wht + (size_t)o32 * HID + k0) = o;
    }
}

// ---------- k_fc: gather-pool -> FC1 -> FC2 -> heads + IoU; 8 proposals, 16 waves ----------
__global__ __launch_bounds__(1024) void k_fc(
    const unsigned short* __restrict__ allmax,
    const unsigned short* __restrict__ W1t,
    const unsigned short* __restrict__ W2t,
    const unsigned short* __restrict__ Wht,
    const float* __restrict__ b1v, const float* __restrict__ b2v,
    const float* __restrict__ bc,  const float* __restrict__ bd,
    const float* __restrict__ props, const int* __restrict__ pbid,
    const float* __restrict__ bbx,   const int* __restrict__ gbid,
    float* __restrict__ out)
{
    __shared__ unsigned short featL[8][1288];   // 20.6 KB
    __shared__ unsigned short h1s[16][264];
    __shared__ unsigned short h2s[16][264];
    __shared__ float gbox[N_][4];
    __shared__ int   gids[N_];

    const int tid = threadIdx.x;
    const int row0 = blockIdx.x * 8;

    if (tid < N_) {
        gbox[tid][0] = bbx[tid * 5 + 0];
        gbox[tid][1] = bbx[tid * 5 + 1];
        gbox[tid][2] = bbx[tid * 5 + 2];
        gbox[tid][3] = bbx[tid * 5 + 3];
        gids[tid] = gbid[tid];
    }

    // ---- gather-pool on first 8 waves: wave = proposal ----
    if (tid < 512) {
        int p = tid >> 6, lane = tid & 63;
        int m = row0 + p;
        float4 bx = *(const float4*)(props + (size_t)m * 4);
        float x1 = rintf(bx.x), y1 = rintf(bx.y);
        float x2 = rintf(bx.z), y2 = rintf(bx.w);
        float rw = fmaxf(x2 - x1 + 1.0f, 1.0f);
        float rh = fmaxf(y2 - y1 + 1.0f, 1.0f);
        float bw = rw * 0.5f, bh = rh * 0.5f;
        int hs0 = __builtin_amdgcn_readfirstlane((int)fminf(fmaxf(y1, 0.f), 7.f));
        int he0 = __builtin_amdgcn_readfirstlane((int)fminf(fmaxf(ceilf(bh) + y1, 0.f), 7.f));
        int hs1 = __builtin_amdgcn_readfirstlane((int)fminf(fmaxf(floorf(bh) + y1, 0.f), 7.f));
        int he1 = __builtin_amdgcn_readfirstlane((int)fminf(fmaxf(ceilf(2.f * bh) + y1, 0.f), 7.f));
        int ws0 = __builtin_amdgcn_readfirstlane((int)fminf(fmaxf(x1, 0.f), 7.f));
        int we0 = __builtin_amdgcn_readfirstlane((int)fminf(fmaxf(ceilf(bw) + x1, 0.f), 7.f));
        int ws1 = __builtin_amdgcn_readfirstlane((int)fminf(fmaxf(floorf(bw) + x1, 0.f), 7.f));
        int we1 = __builtin_amdgcn_readfirstlane((int)fminf(fmaxf(ceilf(2.f * bw) + x1, 0.f), 7.f));
        int bid = __builtin_amdgcn_readfirstlane(pbid[m]);

        int v00 = (he0 > hs0) & (we0 > ws0);
        int v01 = (he0 > hs0) & (we1 > ws1);
        int v10 = (he1 > hs1) & (we0 > ws0);
        int v11 = (he1 > hs1) & (we1 > ws1);
        int yi0 = v00 | v01 ? ivix(hs0, max(he0, hs0 + 1)) : 0;
        int yi1 = v10 | v11 ? ivix(hs1, max(he1, hs1 + 1)) : 0;
        int xi0 = v00 | v10 ? ivix(ws0, max(we0, ws0 + 1)) : 0;
        int xi1 = v01 | v11 ? ivix(ws1, max(we1, ws1 + 1)) : 0;
        const unsigned short* base = allmax + (size_t)bid * NRECT * C_;
        const unsigned short* a00 = base + (size_t)(yi0 * 28 + xi0) * C_;
        const unsigned short* a01 = base + (size_t)(yi0 * 28 + xi1) * C_;
        const unsigned short* a10 = base + (size_t)(yi1 * 28 + xi0) * C_;
        const unsigned short* a11 = base + (size_t)(yi1 * 28 + xi1) * C_;
        float m00 = v00 ? 0.25f : 0.0f;
        float m01 = v01 ? 0.25f : 0.0f;
        float m10 = v10 ? 0.25f : 0.0f;
        float m11 = v11 ? 0.25f : 0.0f;

        #pragma unroll
        for (int it = 0; it < 5; ++it) {
            int c = it * 256 + lane * 4;
            ushort4 u0 = *(const ushort4*)(a00 + c);
            ushort4 u1 = *(const ushort4*)(a01 + c);
            ushort4 u2 = *(const ushort4*)(a10 + c);
            ushort4 u3 = *(const ushort4*)(a11 + c);
            ushort4 o;
            o.x = f2bf(bf2f(u0.x) * m00 + bf2f(u1.x) * m01 + bf2f(u2.x) * m10 + bf2f(u3.x) * m11);
            o.y = f2bf(bf2f(u0.y) * m00 + bf2f(u1.y) * m01 + bf2f(u2.y) * m10 + bf2f(u3.y) * m11);
            o.z = f2bf(bf2f(u0.z) * m00 + bf2f(u1.z) * m01 + bf2f(u2.z) * m10 + bf2f(u3.z) * m11);
            o.w = f2bf(bf2f(u0.w) * m00 + bf2f(u1.w) * m01 + bf2f(u2.w) * m10 + bf2f(u3.w) * m11);
            *(ushort4*)&featL[p][c] = o;
        }
    }
    __syncthreads();

    const int w = tid >> 6, lane = tid & 63;
    const int r = lane & 15, g = lane >> 4;
    const int col0 = w * 16;                  // wave covers 16 cols

    // ---- FC1: A from LDS, B depth-4 register prefetch ----
    f32x4 acc = (f32x4){0.f, 0.f, 0.f, 0.f};
    const unsigned short* arp = featL[r & 7] + g * 8;
    const unsigned short* bp  = W1t + (size_t)(col0 + r) * C_ + g * 8;

    bf16x8 af[4], bf[4];
    #pragma unroll
    for (int i = 0; i < 4; ++i) {
        af[i] = *(const bf16x8*)(arp + i * 32);
        bf[i] = *(const bf16x8*)(bp  + i * 32);
    }
    #pragma unroll
    for (int ks = 4; ks < 40; ++ks) {
        int sl = ks & 3;
        acc = __builtin_amdgcn_mfma_f32_16x16x32_bf16(af[sl], bf[sl], acc, 0, 0, 0);
        af[sl] = *(const bf16x8*)(arp + ks * 32);
        bf[sl] = *(const bf16x8*)(bp  + ks * 32);
    }
    #pragma unroll
    for (int ks = 40; ks < 44; ++ks)
        acc = __builtin_amdgcn_mfma_f32_16x16x32_bf16(af[ks & 3], bf[ks & 3], acc, 0, 0, 0);

    {
        int col = col0 + r;
        float bias = b1v[col];
        #pragma unroll
        for (int i = 0; i < 4; ++i)
            h1s[g * 4 + i][col] = f2bf(fmaxf(acc[i] + bias, 0.f));
    }

    // ---- FC2 B preload (independent of h1s) BEFORE barrier ----
    const unsigned short* bq = W2t + (size_t)(col0 + r) * HID + g * 8;
    bf16x8 u[8];
    #pragma unroll
    for (int ks = 0; ks < 8; ++ks) u[ks] = *(const bf16x8*)(bq + ks * 32);

    __syncthreads();

    // ---- FC2: A from LDS, B preloaded ----
    f32x4 c2 = (f32x4){0.f, 0.f, 0.f, 0.f};
    #pragma unroll
    for (int ks = 0; ks < 8; ++ks) {
        bf16x8 a = *(const bf16x8*)(&h1s[r][ks * 32 + g * 8]);
        c2 = __builtin_amdgcn_mfma_f32_16x16x32_bf16(a, u[ks], c2, 0, 0, 0);
    }
    {
        int col = col0 + r;
        float bias = b2v[col];
        #pragma unroll
        for (int i = 0; i < 4; ++i)
            h2s[g * 4 + i][col] = f2bf(c2[i] + bias);
    }
    __syncthreads();

    // ---- heads on wave 0 (rows 0..7 valid) ----
    if (w == 0) {
        f32x4 acc3[2];
        #pragma unroll
        for (int f = 0; f < 2; ++f) acc3[f] = (f32x4){0.f, 0.f, 0.f, 0.f};
        const unsigned short* bp3 = Wht + (size_t)r * HID + g * 8;
        #pragma unroll
        for (int ks = 0; ks < 8; ++ks) {
            bf16x8 a = *(const bf16x8*)(&h2s[r][ks * 32 + g * 8]);
            #pragma unroll
            for (int f = 0; f < 2; ++f) {
                bf16x8 b = *(const bf16x8*)(bp3 + (size_t)f * 16 * HID + ks * 32);
                acc3[f] = __builtin_amdgcn_mfma_f32_16x16x32_bf16(a, b, acc3[f], 0, 0, 0);
            }
        }
        if (g < 2) {
            #pragma unroll
            for (int f = 0; f < 2; ++f) {
                int col = f * 16 + r;
                #pragma unroll
                for (int i = 0; i < 4; ++i) {
                    int m = row0 + g * 4 + i;
                    if (col < NC)
                        out[(size_t)m * NC + col] = acc3[f][i] + bc[col];
                    else if (col < NC + 4)
                        out[DET_OFF + (size_t)m * 4 + (col - NC)] = acc3[f][i] + bd[col - NC];
                }
            }
        }
    }

    // ---- IoU: waves 0..7, wave w handles proposal row0+w ----
    if (w < 8) {
        int m = row0 + w;
        float4 bxp = *(const float4*)(props + (size_t)m * 4);
        float ap2 = (bxp.z - bxp.x) * (bxp.w - bxp.y);
        int pb = pbid[m];
        float best = 0.0f;
        for (int n = lane; n < N_; n += 64) {
            if (gids[n] == pb) {
                float ix = fmaxf(fminf(bxp.z, gbox[n][2]) - fmaxf(bxp.x, gbox[n][0]), 0.0f);
                float iy = fmaxf(fminf(bxp.w, gbox[n][3]) - fmaxf(bxp.y, gbox[n][1]), 0.0f);
                float inter = ix * iy;
                float ag = (gbox[n][2] - gbox[n][0]) * (gbox[n][3] - gbox[n][1]);
                float un = fmaxf(ap2 + ag - inter, 1e-6f);
                best = fmaxf(best, inter / un);
            }
        }
        #pragma unroll
        for (int off = 32; off; off >>= 1)
            best = fmaxf(best, __shfl_xor(best, off));
        if (lane == 0) out[IOU_OFF + m] = best;
    }
}

extern "C" void kernel_launch(void* const* d_in, const int* in_sizes, int n_in,
                              void* d_out, int out_size, void* d_ws, size_t ws_size,
                              hipStream_t stream) {
    const float* fmap  = (const float*)d_in[0];
    const float* props = (const float*)d_in[1];
    const float* bbx   = (const float*)d_in[2];
    const float* W1    = (const float*)d_in[3];
    const float* b1v   = (const float*)d_in[4];
    const float* W2    = (const float*)d_in[5];
    const float* b2v   = (const float*)d_in[6];
    const float* Wc    = (const float*)d_in[7];
    const float* bc    = (const float*)d_in[8];
    const float* Wd    = (const float*)d_in[9];
    const float* bd    = (const float*)d_in[10];
    const int*   pbid  = (const int*)d_in[11];
    const int*   gbid  = (const int*)d_in[12];
    float* out = (float*)d_out;

    char* ws = (char*)d_ws;
    unsigned short* W1t    = (unsigned short*)(ws + W1T_OFF);
    unsigned short* W2t    = (unsigned short*)(ws + W2T_OFF);
    unsigned short* Wht    = (unsigned short*)(ws + WHT_OFF);
    unsigned short* allmax = (unsigned short*)(ws + AM_OFF);

    k_aux<<<dim3(AUX_BLKS), dim3(256), 0, stream>>>(
        fmap, W1, W2, Wc, Wd, allmax, W1t, W2t, Wht);
    k_fc<<<dim3(M_ / 8), dim3(1024), 0, stream>>>(
        allmax, W1t, W2t, Wht, b1v, b2v, bc, bd, props, pbid, bbx, gbid, out);
}